// Round 4
// baseline (490.443 us; speedup 1.0000x reference)
//
#include <hip/hip_runtime.h>

#define DIM 2048
#define NB 8
#define NT (DIM / 64)   // K-tiles of 64

typedef _Float16 f16;
typedef __attribute__((ext_vector_type(8))) _Float16 f16x8;
typedef __attribute__((ext_vector_type(4))) _Float16 f16x4;
typedef __attribute__((ext_vector_type(2))) _Float16 f16x2;
typedef __attribute__((ext_vector_type(4))) float f32x4;
typedef __attribute__((ext_vector_type(4))) unsigned u32x4;

// ---- float <-> orderable uint key (for atomicMax on floats) ----
__device__ __forceinline__ unsigned fkey(float f) {
    unsigned u = __float_as_uint(f);
    return (u & 0x80000000u) ? ~u : (u | 0x80000000u);
}
__device__ __forceinline__ float fdecode(unsigned k) {
    return (k & 0x80000000u) ? __uint_as_float(k ^ 0x80000000u)
                             : __uint_as_float(~k);
}

// ---- async global->LDS 16B DMA (dest = wave-uniform base + lane*16) ----
__device__ __forceinline__ void gld_lds16(const f16* g, f16* l) {
    __builtin_amdgcn_global_load_lds(
        (const __attribute__((address_space(1))) unsigned*)g,
        (__attribute__((address_space(3))) unsigned*)l, 16, 0, 0);
}

#define BAR() asm volatile("s_barrier" ::: "memory")
#define WAITVM(N) asm volatile("s_waitcnt vmcnt(" #N ")" ::: "memory")

// ---- fp32 -> fp16 conversion, float4 vectorized ----
__global__ __launch_bounds__(256) void k_convert(const float* __restrict__ src,
                                                 f16* __restrict__ dst, int n4) {
    int i = blockIdx.x * 256 + threadIdx.x;
    if (i >= n4) return;
    f32x4 v = ((const f32x4*)src)[i];
    ((f16x4*)dst)[i] = __builtin_convertvector(v, f16x4);
}

// ---- fused: fp32->fp16 convert of x AND column sums over token axis ----
__global__ __launch_bounds__(256) void k_prep(const float* __restrict__ x,
                                              f16* __restrict__ Xf,
                                              float* __restrict__ vsum) {
    const int b  = blockIdx.z;
    const int c0 = blockIdx.x * 1024 + threadIdx.x * 4;
    const int n0 = blockIdx.y * 64;
    const float* px = x  + ((size_t)b * DIM + n0) * DIM + c0;
    f16*         pd = Xf + ((size_t)b * DIM + n0) * DIM + c0;
    f32x4 s = (f32x4){0.f, 0.f, 0.f, 0.f};
    #pragma unroll 8
    for (int n = 0; n < 64; ++n) {
        f32x4 v = *(const f32x4*)(px + (size_t)n * DIM);
        *(f16x4*)(pd + (size_t)n * DIM) = __builtin_convertvector(v, f16x4);
        s += v;
    }
    atomicAdd(&vsum[b * DIM + c0 + 0], s.x);
    atomicAdd(&vsum[b * DIM + c0 + 1], s.y);
    atomicAdd(&vsum[b * DIM + c0 + 2], s.z);
    atomicAdd(&vsum[b * DIM + c0 + 3], s.w);
}

// ---- column sums of x over token axis (fallback paths only) ----
__global__ __launch_bounds__(256) void k_colsum(const float* __restrict__ x,
                                                float* __restrict__ vsum) {
    int b = blockIdx.z;
    int c = blockIdx.x * 256 + threadIdx.x;
    int n0 = blockIdx.y * (DIM / 8);
    const float* p = x + ((size_t)b * DIM + n0) * DIM + c;
    float s = 0.f;
    #pragma unroll 8
    for (int n = 0; n < DIM / 8; ++n) s += p[(size_t)n * DIM];
    atomicAdd(&vsum[b * DIM + c], s);
}

// ---- Gram v2: G_b = X_b @ X_b^T, 128^2 tile, 4 waves, counted-vmcnt
//      two-window schedule (port of the verified k_attn256 core) ----
// PhX(t): all frag reads (A 8, B 8) from buf p=t&1 + 16 MFMA (j=0,1); BAR.
// PhY(t): stage(t+2, A) + stage(t+2, B) into buf p (both regions fully read
//         in PhX, one barrier earlier) + 16 MFMA (j=2,3); WAITVM(8); BAR.
// vmcnt ledger: entering PhX(t) outstanding = {t+1}:8; PhY issues {t+2}:8
// -> 16; WAITVM(8) completes {t+1}. Tail t>=NT-2: nothing issued -> WAITVM(0).
__global__ __launch_bounds__(256, 2)
void k_gram2(const f16* __restrict__ Xall, f16* __restrict__ Gall,
             unsigned long xStride, unsigned long gStride) {
    const int b = blockIdx.y;
    const f16* X = Xall + (size_t)b * xStride;
    f16* G = Gall + (size_t)b * gStride;

    int t0 = blockIdx.x;
    int br = (int)((sqrtf(8.f * t0 + 1.f) - 1.f) * 0.5f);
    while ((br + 1) * (br + 2) / 2 <= t0) ++br;
    while (br * (br + 1) / 2 > t0) --br;
    int bc = t0 - br * (br + 1) / 2;   // bc <= br

    __shared__ __align__(16) f16 sm[2][2][128 * 64];   // 64 KiB -> 2 blocks/CU

    const int tid  = threadIdx.x;
    const int ln   = tid & 63;
    const int wv   = tid >> 6;         // 4 waves
    const int wm   = wv >> 1;
    const int wn   = wv & 1;
    const int l15  = ln & 15;
    const int quad = ln >> 4;
    const int swz  = l15 & 7;
    const int cc0  = (quad ^ swz) * 8;
    const int cc1  = ((4 | quad) ^ swz) * 8;
    const int lrow = ln >> 3;
    const int lchunk = (ln & 7) ^ lrow;

    f32x4 acc[4][4];
    #pragma unroll
    for (int i = 0; i < 4; ++i)
        #pragma unroll
        for (int j = 0; j < 4; ++j) acc[i][j] = (f32x4){0.f, 0.f, 0.f, 0.f};

    auto stage = [&](int tt, int op) {   // op 0 = A (rows br), 1 = B (rows bc)
        if (tt >= NT) return;
        const int rowb = (op ? bc : br) * 128;
        const f16* gp = X + (size_t)(rowb + wv * 32 + lrow) * DIM + tt * 64 + lchunk * 8;
        f16* lp = (f16*)sm[tt & 1][op] + (wv * 32) * 64 + ln * 8;
        #pragma unroll
        for (int u = 0; u < 4; ++u)
            gld_lds16(gp + (size_t)(u * 8) * DIM, lp + u * 512);
    };

    f16x8 af[4][2], bf[4][2];

    // prologue: tiles 0 and 1 in flight; wait tile 0
    stage(0, 0); stage(0, 1);
    stage(1, 0); stage(1, 1);
    WAITVM(8);
    BAR();

    for (int t = 0; t < NT; ++t) {
        const f16* LA = (const f16*)sm[t & 1][0];
        const f16* LB = (const f16*)sm[t & 1][1];
        // ---- PhX: all 16 frag reads + MFMA j=0,1
        #pragma unroll
        for (int i = 0; i < 4; ++i) {
            const f16* pa = LA + (wm * 64 + i * 16 + l15) * 64;
            af[i][0] = *(const f16x8*)(pa + cc0);
            af[i][1] = *(const f16x8*)(pa + cc1);
        }
        #pragma unroll
        for (int j = 0; j < 4; ++j) {
            const f16* pb = LB + (wn * 64 + j * 16 + l15) * 64;
            bf[j][0] = *(const f16x8*)(pb + cc0);
            bf[j][1] = *(const f16x8*)(pb + cc1);
        }
        __builtin_amdgcn_s_setprio(1);
        #pragma unroll
        for (int i = 0; i < 4; ++i)
            #pragma unroll
            for (int j = 0; j < 2; ++j)
                #pragma unroll
                for (int kk = 0; kk < 2; ++kk)
                    acc[i][j] = __builtin_amdgcn_mfma_f32_16x16x32_f16(af[i][kk], bf[j][kk], acc[i][j], 0, 0, 0);
        __builtin_amdgcn_s_setprio(0);
        BAR();
        // ---- PhY: stage t+2 (regions read in PhX, 1 bar ago) + MFMA j=2,3
        stage(t + 2, 0); stage(t + 2, 1);
        __builtin_amdgcn_s_setprio(1);
        #pragma unroll
        for (int i = 0; i < 4; ++i)
            #pragma unroll
            for (int j = 2; j < 4; ++j)
                #pragma unroll
                for (int kk = 0; kk < 2; ++kk)
                    acc[i][j] = __builtin_amdgcn_mfma_f32_16x16x32_f16(af[i][kk], bf[j][kk], acc[i][j], 0, 0, 0);
        __builtin_amdgcn_s_setprio(0);
        if (t < NT - 2) { WAITVM(8); }
        else            { WAITVM(0); }
        BAR();
    }

    const int wr = wm * 64, wc = wn * 64;

    // own tile: direct stores (lanes of a quad write 32B-contiguous runs)
    #pragma unroll
    for (int i = 0; i < 4; ++i)
        #pragma unroll
        for (int j = 0; j < 4; ++j)
            #pragma unroll
            for (int r = 0; r < 4; ++r) {
                int row = br * 128 + wr + i * 16 + quad * 4 + r;
                int col = bc * 128 + wc + j * 16 + l15;
                G[(size_t)row * DIM + col] = (f16)acc[i][j][r];
            }

    if (br != bc) {
        // mirror tile via LDS transpose -> coalesced 16B stores
        __syncthreads();
        f16* T = (f16*)sm;   // 128 x 136 f16 (34.8 KB of the 64 KB)
        #pragma unroll
        for (int i = 0; i < 4; ++i)
            #pragma unroll
            for (int j = 0; j < 4; ++j)
                #pragma unroll
                for (int h = 0; h < 2; ++h) {
                    int row = wr + i * 16 + quad * 4 + h * 2;
                    int col = wc + j * 16 + l15;
                    f16x2 v = {(f16)acc[i][j][h * 2], (f16)acc[i][j][h * 2 + 1]};
                    *(f16x2*)(T + col * 136 + row) = v;
                }
        __syncthreads();
        #pragma unroll
        for (int p = 0; p < 8; ++p) {
            int ch = p * 256 + tid;          // 0..2047
            int rt = ch >> 4, seg = ch & 15;
            f16x8 v = *(const f16x8*)(T + rt * 136 + seg * 8);
            *(f16x8*)(G + (size_t)(bc * 128 + rt) * DIM + br * 128 + seg * 8) = v;
        }
    }
}

// ---- attn tile = scale * Wq @ G_b  (256^2 tile, BK=64, 8 waves, two-phase
//      counted-vmcnt schedule; fused row-max via shfl + atomicMax) ----
__global__ __launch_bounds__(512, 2)
void k_attn256(const f16* __restrict__ Wq, const f16* __restrict__ Gall,
               unsigned* __restrict__ mkey, unsigned long gStride, int batchBase) {
    __shared__ __align__(16) f16 sm[2][2][256 * 64];   // 128 KiB

    const int q  = gridDim.x >> 3;
    const int w  = (blockIdx.x & 7) * q + (blockIdx.x >> 3);   // XCD-chunked, bijective
    const int zi = w >> 6;
    const int br = (w >> 3) & 7;
    const int bc = w & 7;
    const f16* A  = Wq;
    const f16* Bt = Gall + (size_t)zi * gStride;   // G symmetric: rows serve as Bt rows
    const int bi = batchBase + zi;

    const int tid  = threadIdx.x;
    const int ln   = tid & 63;
    const int wv   = tid >> 6;
    const int wm   = wv >> 2;
    const int wn   = wv & 3;
    const int l15  = ln & 15;
    const int quad = ln >> 4;
    const int swz  = l15 & 7;
    const int cc0  = ((quad) ^ swz) * 8;
    const int cc1  = ((4 | quad) ^ swz) * 8;
    const int lrow = ln >> 3;
    const int lchunk = (ln & 7) ^ lrow;

    f32x4 acc[8][4];
    #pragma unroll
    for (int i = 0; i < 8; ++i)
        #pragma unroll
        for (int j = 0; j < 4; ++j) acc[i][j] = (f32x4){0.f, 0.f, 0.f, 0.f};

    auto stage = [&](int t, int s) {
        if (t >= NT) return;
        const int p = t & 1;
        const f16* src; int rowb; f16* L;
        if (s == 0 || s == 3) { src = A;  rowb = br * 256; L = (f16*)sm[p][0]; }
        else                  { src = Bt; rowb = bc * 256; L = (f16*)sm[p][1]; }
        const int h  = (s >= 2) ? 1 : 0;
        const int r0 = h * 128 + wv * 16;
        const f16* gp = src + (size_t)(rowb + r0 + lrow) * DIM + t * 64 + lchunk * 8;
        f16* lp = L + r0 * 64 + ln * 8;
        gld_lds16(gp, lp);
        gld_lds16(gp + (size_t)8 * DIM, lp + 512);
    };

    f16x8 af[4][2], bl[2][2], bh[2][2];

    auto loadA = [&](int qm, const f16* LA) {
        #pragma unroll
        for (int i = 0; i < 4; ++i) {
            const f16* pa = LA + (qm * 128 + wm * 64 + i * 16 + l15) * 64;
            af[i][0] = *(const f16x8*)(pa + cc0);
            af[i][1] = *(const f16x8*)(pa + cc1);
        }
    };
    auto loadB = [&](int qn, const f16* LB, f16x8 (&bf)[2][2]) {
        #pragma unroll
        for (int j = 0; j < 2; ++j) {
            const f16* pb = LB + (qn * 128 + wn * 32 + j * 16 + l15) * 64;
            bf[j][0] = *(const f16x8*)(pb + cc0);
            bf[j][1] = *(const f16x8*)(pb + cc1);
        }
    };
    auto mfmaQ = [&](int qm, int qn, f16x8 (&a)[4][2], f16x8 (&bf)[2][2]) {
        __builtin_amdgcn_s_setprio(1);
        #pragma unroll
        for (int i = 0; i < 4; ++i)
            #pragma unroll
            for (int j = 0; j < 2; ++j)
                #pragma unroll
                for (int kk = 0; kk < 2; ++kk)
                    acc[qm * 4 + i][qn * 2 + j] = __builtin_amdgcn_mfma_f32_16x16x32_f16(
                        a[i][kk], bf[j][kk], acc[qm * 4 + i][qn * 2 + j], 0, 0, 0);
        __builtin_amdgcn_s_setprio(0);
    };

    // prologue: tile 0 complete + 3/4 of tile 1 in flight
    stage(0, 0); stage(0, 1); stage(0, 2); stage(0, 3);
    WAITVM(4);
    stage(1, 0); stage(1, 1); stage(1, 2);
    WAITVM(6);
    BAR();

    for (int t = 0; t < NT; ++t) {
        const f16* LA = (const f16*)sm[t & 1][0];
        const f16* LB = (const f16*)sm[t & 1][1];
        // ---- PhX: 16 reads + 32 MFMA
        loadA(0, LA); loadB(0, LB, bl); loadB(1, LB, bh);
        stage(t + 1, 3);
        mfmaQ(0, 0, af, bl);
        mfmaQ(0, 1, af, bh);
        BAR();
        // ---- PhY: 8 reads (A-high into af regs) + 32 MFMA + publish t+1
        loadA(1, LA);
        stage(t + 2, 0); stage(t + 2, 1); stage(t + 2, 2);
        mfmaQ(1, 0, af, bl);
        mfmaQ(1, 1, af, bh);
        if (t < NT - 2) { WAITVM(6); }
        else            { WAITVM(0); }
        BAR();
    }

    const float scale = 0.0625f;              // (2048/8)^-0.5
    #pragma unroll
    for (int i = 0; i < 8; ++i) {
        const int qm = i >> 2, il = i & 3;
        #pragma unroll
        for (int r = 0; r < 4; ++r) {
            float v = fmaxf(fmaxf(acc[i][0][r], acc[i][1][r]),
                            fmaxf(acc[i][2][r], acc[i][3][r]));
            #pragma unroll
            for (int m = 1; m <= 8; m <<= 1)
                v = fmaxf(v, __shfl_xor(v, m, 64));
            if (l15 == 0) {
                const int row = br * 256 + qm * 128 + wm * 64 + il * 16 + quad * 4 + r;
                atomicMax(&mkey[(size_t)bi * DIM + row], fkey(scale * v));
            }
        }
    }
}

// ---- out[b,i,j] = (vsum[b,i]/2048) * m[b,j] ----
__global__ __launch_bounds__(256) void k_final(const float* __restrict__ vsum,
                                               const unsigned* __restrict__ mkey,
                                               float* __restrict__ out) {
    int gid = blockIdx.x * 256 + threadIdx.x;
    int b   = gid >> 20;
    int rem = gid & 1048575;
    int i   = rem >> 9;
    int jq  = rem & 511;
    float v = vsum[(b << 11) + i] * (1.f / 2048.f);
    u32x4 k = ((const u32x4*)mkey)[(b << 9) + jq];
    f32x4 o;
    o.x = v * fdecode(k.x);
    o.y = v * fdecode(k.y);
    o.z = v * fdecode(k.z);
    o.w = v * fdecode(k.w);
    ((f32x4*)out)[gid] = o;
}

extern "C" void kernel_launch(void* const* d_in, const int* in_sizes, int n_in,
                              void* d_out, int out_size, void* d_ws, size_t ws_size,
                              hipStream_t stream) {
    const float* x  = (const float*)d_in[0];
    const float* Wq = (const float*)d_in[1];
    float* out = (float*)d_out;
    char* ws = (char*)d_ws;

    const size_t elems = (size_t)DIM * DIM;
    unsigned* mkey = (unsigned*)ws;                         // 64 KB
    float*    vsum = (float*)(ws + 65536);                  // 64 KB
    f16*      Wqf  = (f16*)(ws + 131072);                   // 8 MB
    f16*      Xf   = (f16*)(ws + 131072 + elems * 2);

    const size_t need1 = 131072 + elems * 2 * (1 + NB + NB);  // ~142.7 MB
    const size_t need2 = 131072 + elems * 2 * (1 + NB + 1);   // ~84.0 MB

    hipMemsetAsync(ws, 0, 131072, stream);
    k_convert<<<4096, 256, 0, stream>>>(Wq, Wqf, (int)(elems / 4));

    if (ws_size >= need1) {
        f16* G = Xf + NB * elems;
        k_prep<<<dim3(2, 32, NB), 256, 0, stream>>>(x, Xf, vsum);
        k_gram2<<<dim3(136, NB), 256, 0, stream>>>(Xf, G, elems, elems);
        // split into 2 dispatches (2 x 256 blocks = same 2 rounds; surfaces
        // gram/prep in the top-5 counter table)
        k_attn256<<<dim3(256), 512, 0, stream>>>(Wqf, G, mkey, elems, 0);
        k_attn256<<<dim3(256), 512, 0, stream>>>(Wqf, G + (size_t)4 * elems, mkey, elems, 4);
    } else if (ws_size >= need2) {
        f16* G = Xf + NB * elems;
        k_prep<<<dim3(2, 32, NB), 256, 0, stream>>>(x, Xf, vsum);
        for (int b = 0; b < NB; ++b) {
            k_gram2<<<dim3(136, 1), 256, 0, stream>>>(Xf + (size_t)b * elems, G, 0, 0);
            k_attn256<<<dim3(64), 512, 0, stream>>>(Wqf, G, mkey, 0, b);
        }
    } else {
        f16* G = Xf + elems;
        k_colsum<<<dim3(8, 8, 8), 256, 0, stream>>>(x, vsum);
        for (int b = 0; b < NB; ++b) {
            k_convert<<<4096, 256, 0, stream>>>(x + (size_t)b * elems, Xf, (int)(elems / 4));
            k_gram2<<<dim3(136, 1), 256, 0, stream>>>(Xf, G, 0, 0);
            k_attn256<<<dim3(64), 512, 0, stream>>>(Wqf, G, mkey, 0, b);
        }
    }
    k_final<<<32768, 256, 0, stream>>>(vsum, mkey, out);
}

// Round 5
// 458.431 us; speedup vs baseline: 1.0698x; 1.0698x over previous
//
#include <hip/hip_runtime.h>

#define DIM 2048
#define NB 8
#define NT (DIM / 64)   // K-tiles of 64

typedef _Float16 f16;
typedef __attribute__((ext_vector_type(8))) _Float16 f16x8;
typedef __attribute__((ext_vector_type(4))) _Float16 f16x4;
typedef __attribute__((ext_vector_type(2))) _Float16 f16x2;
typedef __attribute__((ext_vector_type(4))) float f32x4;
typedef __attribute__((ext_vector_type(4))) unsigned u32x4;

// ---- float <-> orderable uint key (for atomicMax on floats) ----
__device__ __forceinline__ unsigned fkey(float f) {
    unsigned u = __float_as_uint(f);
    return (u & 0x80000000u) ? ~u : (u | 0x80000000u);
}
__device__ __forceinline__ float fdecode(unsigned k) {
    return (k & 0x80000000u) ? __uint_as_float(k ^ 0x80000000u)
                             : __uint_as_float(~k);
}

// ---- async global->LDS 16B DMA (dest = wave-uniform base + lane*16) ----
__device__ __forceinline__ void gld_lds16(const f16* g, f16* l) {
    __builtin_amdgcn_global_load_lds(
        (const __attribute__((address_space(1))) unsigned*)g,
        (__attribute__((address_space(3))) unsigned*)l, 16, 0, 0);
}

#define BAR() asm volatile("s_barrier" ::: "memory")
#define WAITVM(N) asm volatile("s_waitcnt vmcnt(" #N ")" ::: "memory")

// ---- fp32 -> fp16 conversion, float4 vectorized ----
__global__ __launch_bounds__(256) void k_convert(const float* __restrict__ src,
                                                 f16* __restrict__ dst, int n4) {
    int i = blockIdx.x * 256 + threadIdx.x;
    if (i >= n4) return;
    f32x4 v = ((const f32x4*)src)[i];
    ((f16x4*)dst)[i] = __builtin_convertvector(v, f16x4);
}

// ---- fused: fp32->fp16 convert of x AND column sums over token axis ----
__global__ __launch_bounds__(256) void k_prep(const float* __restrict__ x,
                                              f16* __restrict__ Xf,
                                              float* __restrict__ vsum) {
    const int b  = blockIdx.z;
    const int c0 = blockIdx.x * 1024 + threadIdx.x * 4;
    const int n0 = blockIdx.y * 64;
    const float* px = x  + ((size_t)b * DIM + n0) * DIM + c0;
    f16*         pd = Xf + ((size_t)b * DIM + n0) * DIM + c0;
    f32x4 s = (f32x4){0.f, 0.f, 0.f, 0.f};
    #pragma unroll 8
    for (int n = 0; n < 64; ++n) {
        f32x4 v = *(const f32x4*)(px + (size_t)n * DIM);
        *(f16x4*)(pd + (size_t)n * DIM) = __builtin_convertvector(v, f16x4);
        s += v;
    }
    atomicAdd(&vsum[b * DIM + c0 + 0], s.x);
    atomicAdd(&vsum[b * DIM + c0 + 1], s.y);
    atomicAdd(&vsum[b * DIM + c0 + 2], s.z);
    atomicAdd(&vsum[b * DIM + c0 + 3], s.w);
}

// ---- column sums of x over token axis (fallback paths only) ----
__global__ __launch_bounds__(256) void k_colsum(const float* __restrict__ x,
                                                float* __restrict__ vsum) {
    int b = blockIdx.z;
    int c = blockIdx.x * 256 + threadIdx.x;
    int n0 = blockIdx.y * (DIM / 8);
    const float* p = x + ((size_t)b * DIM + n0) * DIM + c;
    float s = 0.f;
    #pragma unroll 8
    for (int n = 0; n < DIM / 8; ++n) s += p[(size_t)n * DIM];
    atomicAdd(&vsum[b * DIM + c], s);
}

// ---- Gram v2: G_b = X_b @ X_b^T, 128^2 tile, 4 waves, counted-vmcnt
//      two-window schedule + XCD-batch swizzle ----
// Grid = 1088 flat: batch = blockIdx.x & 7 (hw round-robins consecutive ids
// across the 8 XCDs -> each batch pinned to one XCD, its 8 MB X panels stay
// in that XCD's L2), tile = blockIdx.x >> 3 (triangular order per XCD ->
// A-panel run-reuse). Fallback per-batch launches use gridDim.x == 136.
__global__ __launch_bounds__(256, 2)
void k_gram2(const f16* __restrict__ Xall, f16* __restrict__ Gall,
             unsigned long xStride, unsigned long gStride) {
    int b, t0;
    if (gridDim.x == NB * 136) { b = blockIdx.x & 7; t0 = blockIdx.x >> 3; }
    else                       { b = blockIdx.y;     t0 = blockIdx.x;      }
    const f16* X = Xall + (size_t)b * xStride;
    f16* G = Gall + (size_t)b * gStride;

    int br = (int)((sqrtf(8.f * t0 + 1.f) - 1.f) * 0.5f);
    while ((br + 1) * (br + 2) / 2 <= t0) ++br;
    while (br * (br + 1) / 2 > t0) --br;
    int bc = t0 - br * (br + 1) / 2;   // bc <= br

    __shared__ __align__(16) f16 sm[2][2][128 * 64];   // 64 KiB -> 2 blocks/CU

    const int tid  = threadIdx.x;
    const int ln   = tid & 63;
    const int wv   = tid >> 6;         // 4 waves
    const int wm   = wv >> 1;
    const int wn   = wv & 1;
    const int l15  = ln & 15;
    const int quad = ln >> 4;
    const int swz  = l15 & 7;
    const int cc0  = (quad ^ swz) * 8;
    const int cc1  = ((4 | quad) ^ swz) * 8;
    const int lrow = ln >> 3;
    const int lchunk = (ln & 7) ^ lrow;

    f32x4 acc[4][4];
    #pragma unroll
    for (int i = 0; i < 4; ++i)
        #pragma unroll
        for (int j = 0; j < 4; ++j) acc[i][j] = (f32x4){0.f, 0.f, 0.f, 0.f};

    auto stage = [&](int tt, int op) {   // op 0 = A (rows br), 1 = B (rows bc)
        if (tt >= NT) return;
        const int rowb = (op ? bc : br) * 128;
        const f16* gp = X + (size_t)(rowb + wv * 32 + lrow) * DIM + tt * 64 + lchunk * 8;
        f16* lp = (f16*)sm[tt & 1][op] + (wv * 32) * 64 + ln * 8;
        #pragma unroll
        for (int u = 0; u < 4; ++u)
            gld_lds16(gp + (size_t)(u * 8) * DIM, lp + u * 512);
    };

    f16x8 af[4][2], bf[4][2];

    // prologue: tiles 0 and 1 in flight; wait tile 0
    stage(0, 0); stage(0, 1);
    stage(1, 0); stage(1, 1);
    WAITVM(8);
    BAR();

    for (int t = 0; t < NT; ++t) {
        const f16* LA = (const f16*)sm[t & 1][0];
        const f16* LB = (const f16*)sm[t & 1][1];
        // ---- PhX: all 16 frag reads + MFMA j=0,1
        #pragma unroll
        for (int i = 0; i < 4; ++i) {
            const f16* pa = LA + (wm * 64 + i * 16 + l15) * 64;
            af[i][0] = *(const f16x8*)(pa + cc0);
            af[i][1] = *(const f16x8*)(pa + cc1);
        }
        #pragma unroll
        for (int j = 0; j < 4; ++j) {
            const f16* pb = LB + (wn * 64 + j * 16 + l15) * 64;
            bf[j][0] = *(const f16x8*)(pb + cc0);
            bf[j][1] = *(const f16x8*)(pb + cc1);
        }
        __builtin_amdgcn_s_setprio(1);
        #pragma unroll
        for (int i = 0; i < 4; ++i)
            #pragma unroll
            for (int j = 0; j < 2; ++j)
                #pragma unroll
                for (int kk = 0; kk < 2; ++kk)
                    acc[i][j] = __builtin_amdgcn_mfma_f32_16x16x32_f16(af[i][kk], bf[j][kk], acc[i][j], 0, 0, 0);
        __builtin_amdgcn_s_setprio(0);
        BAR();
        // ---- PhY: stage t+2 (regions read in PhX, 1 bar ago) + MFMA j=2,3
        stage(t + 2, 0); stage(t + 2, 1);
        __builtin_amdgcn_s_setprio(1);
        #pragma unroll
        for (int i = 0; i < 4; ++i)
            #pragma unroll
            for (int j = 2; j < 4; ++j)
                #pragma unroll
                for (int kk = 0; kk < 2; ++kk)
                    acc[i][j] = __builtin_amdgcn_mfma_f32_16x16x32_f16(af[i][kk], bf[j][kk], acc[i][j], 0, 0, 0);
        __builtin_amdgcn_s_setprio(0);
        if (t < NT - 2) { WAITVM(8); }
        else            { WAITVM(0); }
        BAR();
    }

    const int wr = wm * 64, wc = wn * 64;

    // own tile: direct stores (lanes of a quad write 32B-contiguous runs)
    #pragma unroll
    for (int i = 0; i < 4; ++i)
        #pragma unroll
        for (int j = 0; j < 4; ++j)
            #pragma unroll
            for (int r = 0; r < 4; ++r) {
                int row = br * 128 + wr + i * 16 + quad * 4 + r;
                int col = bc * 128 + wc + j * 16 + l15;
                G[(size_t)row * DIM + col] = (f16)acc[i][j][r];
            }

    if (br != bc) {
        // mirror tile via LDS transpose -> coalesced 16B stores
        __syncthreads();
        f16* T = (f16*)sm;   // 128 x 136 f16 (34.8 KB of the 64 KB)
        #pragma unroll
        for (int i = 0; i < 4; ++i)
            #pragma unroll
            for (int j = 0; j < 4; ++j)
                #pragma unroll
                for (int h = 0; h < 2; ++h) {
                    int row = wr + i * 16 + quad * 4 + h * 2;
                    int col = wc + j * 16 + l15;
                    f16x2 v = {(f16)acc[i][j][h * 2], (f16)acc[i][j][h * 2 + 1]};
                    *(f16x2*)(T + col * 136 + row) = v;
                }
        __syncthreads();
        #pragma unroll
        for (int p = 0; p < 8; ++p) {
            int ch = p * 256 + tid;          // 0..2047
            int rt = ch >> 4, seg = ch & 15;
            f16x8 v = *(const f16x8*)(T + rt * 136 + seg * 8);
            *(f16x8*)(G + (size_t)(bc * 128 + rt) * DIM + br * 128 + seg * 8) = v;
        }
    }
}

// ---- attn tile = scale * Wq @ G_b  (256^2 tile, BK=64, 8 waves, two-phase
//      counted-vmcnt schedule; fused row-max via shfl + atomicMax) ----
__global__ __launch_bounds__(512, 2)
void k_attn256(const f16* __restrict__ Wq, const f16* __restrict__ Gall,
               unsigned* __restrict__ mkey, unsigned long gStride, int batchBase) {
    __shared__ __align__(16) f16 sm[2][2][256 * 64];   // 128 KiB

    const int q  = gridDim.x >> 3;
    const int w  = (blockIdx.x & 7) * q + (blockIdx.x >> 3);   // XCD-chunked, bijective
    const int zi = w >> 6;
    const int br = (w >> 3) & 7;
    const int bc = w & 7;
    const f16* A  = Wq;
    const f16* Bt = Gall + (size_t)zi * gStride;   // G symmetric: rows serve as Bt rows
    const int bi = batchBase + zi;

    const int tid  = threadIdx.x;
    const int ln   = tid & 63;
    const int wv   = tid >> 6;
    const int wm   = wv >> 2;
    const int wn   = wv & 3;
    const int l15  = ln & 15;
    const int quad = ln >> 4;
    const int swz  = l15 & 7;
    const int cc0  = ((quad) ^ swz) * 8;
    const int cc1  = ((4 | quad) ^ swz) * 8;
    const int lrow = ln >> 3;
    const int lchunk = (ln & 7) ^ lrow;

    f32x4 acc[8][4];
    #pragma unroll
    for (int i = 0; i < 8; ++i)
        #pragma unroll
        for (int j = 0; j < 4; ++j) acc[i][j] = (f32x4){0.f, 0.f, 0.f, 0.f};

    auto stage = [&](int t, int s) {
        if (t >= NT) return;
        const int p = t & 1;
        const f16* src; int rowb; f16* L;
        if (s == 0 || s == 3) { src = A;  rowb = br * 256; L = (f16*)sm[p][0]; }
        else                  { src = Bt; rowb = bc * 256; L = (f16*)sm[p][1]; }
        const int h  = (s >= 2) ? 1 : 0;
        const int r0 = h * 128 + wv * 16;
        const f16* gp = src + (size_t)(rowb + r0 + lrow) * DIM + t * 64 + lchunk * 8;
        f16* lp = L + r0 * 64 + ln * 8;
        gld_lds16(gp, lp);
        gld_lds16(gp + (size_t)8 * DIM, lp + 512);
    };

    f16x8 af[4][2], bl[2][2], bh[2][2];

    auto loadA = [&](int qm, const f16* LA) {
        #pragma unroll
        for (int i = 0; i < 4; ++i) {
            const f16* pa = LA + (qm * 128 + wm * 64 + i * 16 + l15) * 64;
            af[i][0] = *(const f16x8*)(pa + cc0);
            af[i][1] = *(const f16x8*)(pa + cc1);
        }
    };
    auto loadB = [&](int qn, const f16* LB, f16x8 (&bf)[2][2]) {
        #pragma unroll
        for (int j = 0; j < 2; ++j) {
            const f16* pb = LB + (qn * 128 + wn * 32 + j * 16 + l15) * 64;
            bf[j][0] = *(const f16x8*)(pb + cc0);
            bf[j][1] = *(const f16x8*)(pb + cc1);
        }
    };
    auto mfmaQ = [&](int qm, int qn, f16x8 (&a)[4][2], f16x8 (&bf)[2][2]) {
        __builtin_amdgcn_s_setprio(1);
        #pragma unroll
        for (int i = 0; i < 4; ++i)
            #pragma unroll
            for (int j = 0; j < 2; ++j)
                #pragma unroll
                for (int kk = 0; kk < 2; ++kk)
                    acc[qm * 4 + i][qn * 2 + j] = __builtin_amdgcn_mfma_f32_16x16x32_f16(
                        a[i][kk], bf[j][kk], acc[qm * 4 + i][qn * 2 + j], 0, 0, 0);
        __builtin_amdgcn_s_setprio(0);
    };

    // prologue: tile 0 complete + 3/4 of tile 1 in flight
    stage(0, 0); stage(0, 1); stage(0, 2); stage(0, 3);
    WAITVM(4);
    stage(1, 0); stage(1, 1); stage(1, 2);
    WAITVM(6);
    BAR();

    for (int t = 0; t < NT; ++t) {
        const f16* LA = (const f16*)sm[t & 1][0];
        const f16* LB = (const f16*)sm[t & 1][1];
        // ---- PhX: 16 reads + 32 MFMA
        loadA(0, LA); loadB(0, LB, bl); loadB(1, LB, bh);
        stage(t + 1, 3);
        mfmaQ(0, 0, af, bl);
        mfmaQ(0, 1, af, bh);
        BAR();
        // ---- PhY: 8 reads (A-high into af regs) + 32 MFMA + publish t+1
        loadA(1, LA);
        stage(t + 2, 0); stage(t + 2, 1); stage(t + 2, 2);
        mfmaQ(1, 0, af, bl);
        mfmaQ(1, 1, af, bh);
        if (t < NT - 2) { WAITVM(6); }
        else            { WAITVM(0); }
        BAR();
    }

    const float scale = 0.0625f;              // (2048/8)^-0.5
    #pragma unroll
    for (int i = 0; i < 8; ++i) {
        const int qm = i >> 2, il = i & 3;
        #pragma unroll
        for (int r = 0; r < 4; ++r) {
            float v = fmaxf(fmaxf(acc[i][0][r], acc[i][1][r]),
                            fmaxf(acc[i][2][r], acc[i][3][r]));
            #pragma unroll
            for (int m = 1; m <= 8; m <<= 1)
                v = fmaxf(v, __shfl_xor(v, m, 64));
            if (l15 == 0) {
                const int row = br * 256 + qm * 128 + wm * 64 + il * 16 + quad * 4 + r;
                atomicMax(&mkey[(size_t)bi * DIM + row], fkey(scale * v));
            }
        }
    }
}

// ---- out[b,i,j] = (vsum[b,i]/2048) * m[b,j] ----
__global__ __launch_bounds__(256) void k_final(const float* __restrict__ vsum,
                                               const unsigned* __restrict__ mkey,
                                               float* __restrict__ out) {
    int gid = blockIdx.x * 256 + threadIdx.x;
    int b   = gid >> 20;
    int rem = gid & 1048575;
    int i   = rem >> 9;
    int jq  = rem & 511;
    float v = vsum[(b << 11) + i] * (1.f / 2048.f);
    u32x4 k = ((const u32x4*)mkey)[(b << 9) + jq];
    f32x4 o;
    o.x = v * fdecode(k.x);
    o.y = v * fdecode(k.y);
    o.z = v * fdecode(k.z);
    o.w = v * fdecode(k.w);
    ((f32x4*)out)[gid] = o;
}

extern "C" void kernel_launch(void* const* d_in, const int* in_sizes, int n_in,
                              void* d_out, int out_size, void* d_ws, size_t ws_size,
                              hipStream_t stream) {
    const float* x  = (const float*)d_in[0];
    const float* Wq = (const float*)d_in[1];
    float* out = (float*)d_out;
    char* ws = (char*)d_ws;

    const size_t elems = (size_t)DIM * DIM;
    unsigned* mkey = (unsigned*)ws;                         // 64 KB
    float*    vsum = (float*)(ws + 65536);                  // 64 KB
    f16*      Wqf  = (f16*)(ws + 131072);                   // 8 MB
    f16*      Xf   = (f16*)(ws + 131072 + elems * 2);

    const size_t need1 = 131072 + elems * 2 * (1 + NB + NB);  // ~142.7 MB
    const size_t need2 = 131072 + elems * 2 * (1 + NB + 1);   // ~84.0 MB

    hipMemsetAsync(ws, 0, 131072, stream);
    k_convert<<<4096, 256, 0, stream>>>(Wq, Wqf, (int)(elems / 4));

    if (ws_size >= need1) {
        f16* G = Xf + NB * elems;
        k_prep<<<dim3(2, 32, NB), 256, 0, stream>>>(x, Xf, vsum);
        // flat grid + XCD-batch swizzle (batch = blk & 7 -> one batch per XCD)
        k_gram2<<<dim3(NB * 136), 256, 0, stream>>>(Xf, G, elems, elems);
        k_attn256<<<dim3(256), 512, 0, stream>>>(Wqf, G, mkey, elems, 0);
        k_attn256<<<dim3(256), 512, 0, stream>>>(Wqf, G + (size_t)4 * elems, mkey, elems, 4);
    } else if (ws_size >= need2) {
        f16* G = Xf + NB * elems;
        k_prep<<<dim3(2, 32, NB), 256, 0, stream>>>(x, Xf, vsum);
        for (int b = 0; b < NB; ++b) {
            k_gram2<<<dim3(136, 1), 256, 0, stream>>>(Xf + (size_t)b * elems, G, 0, 0);
            k_attn256<<<dim3(64), 512, 0, stream>>>(Wqf, G, mkey, 0, b);
        }
    } else {
        f16* G = Xf + elems;
        k_colsum<<<dim3(8, 8, 8), 256, 0, stream>>>(x, vsum);
        for (int b = 0; b < NB; ++b) {
            k_convert<<<4096, 256, 0, stream>>>(x + (size_t)b * elems, Xf, (int)(elems / 4));
            k_gram2<<<dim3(136, 1), 256, 0, stream>>>(Xf, G, 0, 0);
            k_attn256<<<dim3(64), 512, 0, stream>>>(Wqf, G, mkey, 0, b);
        }
    }
    k_final<<<32768, 256, 0, stream>>>(vsum, mkey, out);
}